// Round 1
// baseline (1228.222 us; speedup 1.0000x reference)
//
#include <hip/hip_runtime.h>
#include <math.h>

#define BB 64
#define NN 197
#define HH 10
#define DD 64
#define CC 640
#define C3 1920
#define LR 64
#define MTOT (BB*NN)          // 12608
#define SCALE 0.125f

__device__ __forceinline__ float dot4(float4 a, float4 b) {
  float s = a.x*b.x;
  s = fmaf(a.y, b.y, s);
  s = fmaf(a.z, b.z, s);
  s = fmaf(a.w, b.w, s);
  return s;
}

// ---------------------------------------------------------------------------
// K1: w_eff[1920,640] = perm3(w_qkv + (lora_a @ lora_b)^T)
// perm3 on 1920 rows: out row i <- src row 3*(i%640) + i/640
// ---------------------------------------------------------------------------
__global__ __launch_bounds__(256) void k_weff(
    const float* __restrict__ w_qkv, const float* __restrict__ la,
    const float* __restrict__ lb, float* __restrict__ weff) {
  int idx = blockIdx.x * 256 + threadIdx.x;      // grid covers 1920*640 exactly
  int i = idx / CC, j = idx % CC;
  int src = 3 * (i % CC) + (i / CC);
  float acc = w_qkv[(size_t)src * CC + j];
  const float* laj = la + (size_t)j * LR;
  const float* lbs = lb + src;
  #pragma unroll 8
  for (int r = 0; r < LR; ++r) acc = fmaf(laj[r], lbs[(size_t)r * C3], acc);
  weff[(size_t)i * CC + j] = acc;
}

// ---------------------------------------------------------------------------
// K2/K6: C[M,Nc] = A[M,K] @ Bm(rows maybe perm3-640)[Nc,K]^T + bias[Nc]
// 128x128 tile, BK=16, 256 threads, 8x8 accum per thread.
// ---------------------------------------------------------------------------
__device__ __forceinline__ int perm640(int i) {
  return (i < 214) ? 3 * i : (i < 427 ? 3 * (i - 214) + 1 : 3 * (i - 427) + 2);
}

template<int PERM>
__global__ __launch_bounds__(256) void k_gemm_nt(
    const float* __restrict__ A, const float* __restrict__ Bm,
    const float* __restrict__ bias, float* __restrict__ Cc,
    int M, int Nc, int K) {
  __shared__ float As[16][132];
  __shared__ float Bs[16][132];
  int t = threadIdx.x;
  int m0 = blockIdx.x * 128, n0 = blockIdx.y * 128;
  int tx = t & 15, ty = t >> 4;
  float acc[8][8];
  #pragma unroll
  for (int i = 0; i < 8; ++i)
    #pragma unroll
    for (int j = 0; j < 8; ++j) acc[i][j] = 0.f;

  for (int k0 = 0; k0 < K; k0 += 16) {
    #pragma unroll
    for (int u = 0; u < 2; ++u) {
      int id = t + u * 256;         // 0..511
      int row = id >> 2, kq = id & 3;
      int gr = m0 + row;
      float4 v = make_float4(0.f, 0.f, 0.f, 0.f);
      if (gr < M) v = *(const float4*)(A + (size_t)gr * K + k0 + 4 * kq);
      As[4*kq+0][row] = v.x; As[4*kq+1][row] = v.y;
      As[4*kq+2][row] = v.z; As[4*kq+3][row] = v.w;
      int gn = n0 + row;            // always < Nc (grid exact in y)
      int sr = PERM ? perm640(gn) : gn;
      float4 wv = *(const float4*)(Bm + (size_t)sr * K + k0 + 4 * kq);
      Bs[4*kq+0][row] = wv.x; Bs[4*kq+1][row] = wv.y;
      Bs[4*kq+2][row] = wv.z; Bs[4*kq+3][row] = wv.w;
    }
    __syncthreads();
    #pragma unroll
    for (int kk = 0; kk < 16; ++kk) {
      float4 a0 = *(const float4*)&As[kk][4 * ty];
      float4 a1 = *(const float4*)&As[kk][64 + 4 * ty];
      float4 b0 = *(const float4*)&Bs[kk][4 * tx];
      float4 b1 = *(const float4*)&Bs[kk][64 + 4 * tx];
      float av[8] = {a0.x, a0.y, a0.z, a0.w, a1.x, a1.y, a1.z, a1.w};
      float bv[8] = {b0.x, b0.y, b0.z, b0.w, b1.x, b1.y, b1.z, b1.w};
      #pragma unroll
      for (int i = 0; i < 8; ++i)
        #pragma unroll
        for (int j = 0; j < 8; ++j)
          acc[i][j] = fmaf(av[i], bv[j], acc[i][j]);
    }
    __syncthreads();
  }

  float4 bias0 = *(const float4*)(bias + n0 + 4 * tx);
  float4 bias1 = *(const float4*)(bias + n0 + 64 + 4 * tx);
  #pragma unroll
  for (int i = 0; i < 8; ++i) {
    int row = m0 + (i < 4 ? 4 * ty + i : 64 + 4 * ty + (i - 4));
    if (row < M) {
      float4 o0 = make_float4(acc[i][0] + bias0.x, acc[i][1] + bias0.y,
                              acc[i][2] + bias0.z, acc[i][3] + bias0.w);
      float4 o1 = make_float4(acc[i][4] + bias1.x, acc[i][5] + bias1.y,
                              acc[i][6] + bias1.z, acc[i][7] + bias1.w);
      *(float4*)(Cc + (size_t)row * Nc + n0 + 4 * tx) = o0;
      *(float4*)(Cc + (size_t)row * Nc + n0 + 64 + 4 * tx) = o1;
    }
  }
}

// ---------------------------------------------------------------------------
// K4: per (b,h): scores = (Q K^T + gather(Pv,fv)+gather(Ph,fh)) * scale,
// softmax rows, write probs to attnP[bh][197][200] (cols 197..199 zeroed).
// Pv/Ph computed in-kernel per q row (q . tab_k_{v,h}[t]).
// ---------------------------------------------------------------------------
__global__ __launch_bounds__(256) void k_scores(
    const float* __restrict__ qkv, const float* __restrict__ tkv,
    const float* __restrict__ tkh, float* __restrict__ attnP) {
  __shared__ float4 Kt4[16][201];      // [d4][k]  (K rows, d-major float4)
  __shared__ float4 Tk4[16][65];       // [d4][c]  c<30: tab_k_v, 32..61: tab_k_h
  __shared__ float4 Q4w[4][16][4];     // [wave][d4][r]
  __shared__ float  PvPh[4][4][64];    // [wave][r][c]
  int bh = blockIdx.x;
  int b = bh / HH, h = bh % HH;
  int t = threadIdx.x, w = t >> 6, l = t & 63;
  const float* qbase = qkv + (size_t)b * NN * C3 + h * DD;

  for (int id = t; id < NN * 16; id += 256) {
    int k = id >> 4, d4 = id & 15;
    Kt4[d4][k] = *(const float4*)(qbase + (size_t)k * C3 + CC + 4 * d4);
  }
  for (int id = t; id < 1024; id += 256) {
    int c = id >> 4, d4 = id & 15;
    float4 v = make_float4(0.f, 0.f, 0.f, 0.f);
    if (c < 30) v = *(const float4*)(tkv + c * DD + 4 * d4);
    else if (c >= 32 && c < 62) v = *(const float4*)(tkh + (c - 32) * DD + 4 * d4);
    Tk4[d4][c] = v;
  }
  __syncthreads();

  float* attnBase = attnP + (size_t)bh * NN * 200;
  for (int g = w; g < 50; g += 4) {
    int q0 = 4 * g;
    {
      int r = l >> 4, d4 = l & 15;
      int q = q0 + r;
      float4 v = make_float4(0.f, 0.f, 0.f, 0.f);
      if (q < NN) v = *(const float4*)(qbase + (size_t)q * C3 + 4 * d4);
      Q4w[w][d4][r] = v;
    }
    // Pv/Ph: lane l computes col l
    float pv[4] = {0.f, 0.f, 0.f, 0.f};
    #pragma unroll
    for (int d4 = 0; d4 < 16; ++d4) {
      float4 tb = Tk4[d4][l];
      #pragma unroll
      for (int r = 0; r < 4; ++r) pv[r] += dot4(Q4w[w][d4][r], tb);
    }
    #pragma unroll
    for (int r = 0; r < 4; ++r) PvPh[w][r][l] = pv[r];

    // scores: lane l owns k = l, l+64, l+128, (l+192 if l<5)
    float sc[4][4];
    #pragma unroll
    for (int r = 0; r < 4; ++r)
      #pragma unroll
      for (int i = 0; i < 4; ++i) sc[r][i] = 0.f;
    #pragma unroll
    for (int d4 = 0; d4 < 16; ++d4) {
      float4 q4[4];
      #pragma unroll
      for (int r = 0; r < 4; ++r) q4[r] = Q4w[w][d4][r];
      float4 kv = Kt4[d4][l];
      #pragma unroll
      for (int r = 0; r < 4; ++r) sc[r][0] += dot4(q4[r], kv);
      kv = Kt4[d4][l + 64];
      #pragma unroll
      for (int r = 0; r < 4; ++r) sc[r][1] += dot4(q4[r], kv);
      kv = Kt4[d4][l + 128];
      #pragma unroll
      for (int r = 0; r < 4; ++r) sc[r][2] += dot4(q4[r], kv);
      if (l < 5) {
        kv = Kt4[d4][l + 192];
        #pragma unroll
        for (int r = 0; r < 4; ++r) sc[r][3] += dot4(q4[r], kv);
      }
    }
    #pragma unroll
    for (int r = 0; r < 4; ++r) {
      int q = q0 + r;
      float s[4];
      #pragma unroll
      for (int i = 0; i < 4; ++i) {
        int k = l + 64 * i;
        if (k < NN && q < NN) {
          int fv, fh;
          if (q == 0 || k == 0) { fv = 0; fh = 0; }
          else {
            fv = (k - 1) / 14 - (q - 1) / 14 + 15;
            fh = (k - 1) % 14 - (q - 1) % 14 + 15;
          }
          s[i] = (sc[r][i] + PvPh[w][r][fv] + PvPh[w][r][32 + fh]) * SCALE;
        } else s[i] = -INFINITY;
      }
      float m = fmaxf(fmaxf(s[0], s[1]), fmaxf(s[2], s[3]));
      #pragma unroll
      for (int off = 32; off >= 1; off >>= 1) m = fmaxf(m, __shfl_xor(m, off));
      float e[4], sum = 0.f;
      #pragma unroll
      for (int i = 0; i < 4; ++i) { e[i] = __expf(s[i] - m); sum += e[i]; }
      #pragma unroll
      for (int off = 32; off >= 1; off >>= 1) sum += __shfl_xor(sum, off);
      float inv = 1.f / sum;
      if (q < NN) {
        float* rowp = attnBase + (size_t)q * 200;
        #pragma unroll
        for (int i = 0; i < 3; ++i) rowp[l + 64 * i] = e[i] * inv;
        int k3 = l + 192;
        if (k3 < NN) rowp[k3] = e[3] * inv;
        else if (k3 < 200) rowp[k3] = 0.f;
      }
    }
  }
}

// ---------------------------------------------------------------------------
// K5: per (b,h): out[q,d] = sum_k p*V  +  Av @ tab_v_v + Ah @ tab_v_h
// Av[t] = sum of probs in v-bucket t (runs of 14 consecutive k), Ah strided.
// ---------------------------------------------------------------------------
__global__ __launch_bounds__(256) void k_av(
    const float* __restrict__ qkv, const float* __restrict__ attnP,
    const float* __restrict__ tvv, const float* __restrict__ tvh,
    float* __restrict__ omid) {
  __shared__ float Vt[64][212];        // [d][k], k padded to 200+ (cols>=197 zero)
  __shared__ float pL[4][4][200];      // [wave][r][k]
  __shared__ float AvAh[4][4][2][32];  // [wave][r][{v,h}][bucket]
  int bh = blockIdx.x, b = bh / HH, h = bh % HH;
  int t = threadIdx.x, w = t >> 6, l = t & 63;
  const float* vbase = qkv + (size_t)b * NN * C3 + 2 * CC + h * DD;

  for (int id = t; id < 200 * 16; id += 256) {
    int k = id >> 4, d4 = id & 15;
    float4 v = make_float4(0.f, 0.f, 0.f, 0.f);
    if (k < NN) v = *(const float4*)(vbase + (size_t)k * C3 + 4 * d4);
    Vt[4*d4+0][k] = v.x; Vt[4*d4+1][k] = v.y;
    Vt[4*d4+2][k] = v.z; Vt[4*d4+3][k] = v.w;
  }
  __syncthreads();

  const float* attnBase = attnP + (size_t)bh * NN * 200;
  float* obase = omid + (size_t)b * NN * CC + h * DD;
  for (int g = w; g < 50; g += 4) {
    int q0 = 4 * g;
    for (int id = l; id < 200; id += 64) {
      int r = id / 50, k4 = id % 50;
      int q = q0 + r;
      float4 v = make_float4(0.f, 0.f, 0.f, 0.f);
      if (q < NN) v = *(const float4*)(attnBase + (size_t)q * 200 + 4 * k4);
      *(float4*)&pL[w][r][4 * k4] = v;
    }
    float out[4] = {0.f, 0.f, 0.f, 0.f};
    const float* vrow = &Vt[l][0];
    #pragma unroll 5
    for (int k4 = 0; k4 < 50; ++k4) {
      float4 v4 = *(const float4*)(vrow + 4 * k4);
      #pragma unroll
      for (int r = 0; r < 4; ++r)
        out[r] += dot4(*(const float4*)&pL[w][r][4 * k4], v4);
    }
    // bucketed rel sums
    #pragma unroll
    for (int r = 0; r < 4; ++r) {
      int q = q0 + r;
      float av = 0.f, ah = 0.f;
      if (q == 0) {
        if (l == 0) {
          float ss = 0.f;
          for (int k = 0; k < NN; ++k) ss += pL[w][r][k];
          av = ss; ah = ss;
        }
      } else if (q < NN) {
        int gq = (q - 1) / 14, cq = (q - 1) % 14;
        int gg = l - 15 + gq;
        if (gg >= 0 && gg < 14) {
          int base = 1 + 14 * gg;
          #pragma unroll
          for (int jj = 0; jj < 14; ++jj) av += pL[w][r][base + jj];
        }
        int cc2 = l - 15 + cq;
        if (cc2 >= 0 && cc2 < 14) {
          #pragma unroll
          for (int ii = 0; ii < 14; ++ii) ah += pL[w][r][1 + cc2 + 14 * ii];
        }
        if (l == 0) { av += pL[w][r][0]; ah += pL[w][r][0]; }
      }
      if (l < 32) { AvAh[w][r][0][l] = av; AvAh[w][r][1][l] = ah; }
    }
    #pragma unroll 1
    for (int tt = 0; tt < 30; ++tt) {
      float vv = tvv[tt * DD + l];
      float vh = tvh[tt * DD + l];
      #pragma unroll
      for (int r = 0; r < 4; ++r)
        out[r] += AvAh[w][r][0][tt] * vv + AvAh[w][r][1][tt] * vh;
    }
    #pragma unroll
    for (int r = 0; r < 4; ++r) {
      int q = q0 + r;
      if (q < NN) obase[(size_t)q * CC + l] = out[r];
    }
  }
}

// ---------------------------------------------------------------------------
extern "C" void kernel_launch(void* const* d_in, const int* in_sizes, int n_in,
                              void* d_out, int out_size, void* d_ws, size_t ws_size,
                              hipStream_t stream) {
  (void)in_sizes; (void)n_in; (void)out_size; (void)ws_size;
  const float* x     = (const float*)d_in[0];
  const float* w_qkv = (const float*)d_in[1];
  const float* b_qkv = (const float*)d_in[2];
  const float* la    = (const float*)d_in[3];
  const float* lb    = (const float*)d_in[4];
  const float* tkv   = (const float*)d_in[5];
  const float* tkh   = (const float*)d_in[6];
  const float* tvv   = (const float*)d_in[7];
  const float* tvh   = (const float*)d_in[8];
  const float* wp    = (const float*)d_in[9];
  const float* b_p   = (const float*)d_in[10];

  float* ws   = (float*)d_ws;
  float* qkv  = ws;                                     // 12608*1920
  float* attn = qkv + (size_t)MTOT * C3;                // 640*197*200
  float* weff = attn + (size_t)BB * HH * NN * 200;      // 1920*640
  float* omid = weff + (size_t)C3 * CC;                 // 12608*640

  k_weff<<<(C3 * CC) / 256, 256, 0, stream>>>(w_qkv, la, lb, weff);

  dim3 g1((MTOT + 127) / 128, C3 / 128);
  k_gemm_nt<0><<<g1, dim3(256), 0, stream>>>(x, weff, b_qkv, qkv, MTOT, C3, CC);

  k_scores<<<BB * HH, 256, 0, stream>>>(qkv, tkv, tkh, attn);
  k_av<<<BB * HH, 256, 0, stream>>>(qkv, attn, tvv, tvh, omid);

  dim3 g2((MTOT + 127) / 128, CC / 128);
  k_gemm_nt<1><<<g2, dim3(256), 0, stream>>>(omid, wp, b_p, (float*)d_out, MTOT, CC, CC);
}

// Round 3
// 953.819 us; speedup vs baseline: 1.2877x; 1.2877x over previous
//
#include <hip/hip_runtime.h>
#include <math.h>

#define BB 64
#define NN 197
#define HH 10
#define DD 64
#define CC 640
#define C3 1920
#define LR 64
#define MTOT (BB*NN)          // 12608
#define SCALE 0.125f

typedef unsigned short u16;
typedef __bf16 bf16x8 __attribute__((ext_vector_type(8)));
typedef float f32x4 __attribute__((ext_vector_type(4)));

__device__ __forceinline__ float dot4(float4 a, float4 b) {
  float s = a.x*b.x;
  s = fmaf(a.y, b.y, s);
  s = fmaf(a.z, b.z, s);
  s = fmaf(a.w, b.w, s);
  return s;
}

__device__ __forceinline__ void split_bf16(float f, u16& hi, u16& lo) {
  unsigned u = __float_as_uint(f);
  unsigned r = u + 0x7FFF + ((u >> 16) & 1);
  u16 hb = (u16)(r >> 16);
  float fh = __uint_as_float((unsigned)hb << 16);
  float dl = f - fh;
  unsigned u2 = __float_as_uint(dl);
  unsigned r2 = u2 + 0x7FFF + ((u2 >> 16) & 1);
  hi = hb; lo = (u16)(r2 >> 16);
}

// ---------------------------------------------------------------------------
// K1: w_eff = perm3(w_qkv + (lora_a @ lora_b)^T) -> bf16 hi/lo split
// ---------------------------------------------------------------------------
__global__ __launch_bounds__(256) void k_weff(
    const float* __restrict__ w_qkv, const float* __restrict__ la,
    const float* __restrict__ lb, u16* __restrict__ whi, u16* __restrict__ wlo) {
  int idx = blockIdx.x * 256 + threadIdx.x;      // covers 1920*640
  int i = idx / CC, j = idx % CC;
  int src = 3 * (i % CC) + (i / CC);
  float acc = w_qkv[(size_t)src * CC + j];
  const float* laj = la + (size_t)j * LR;
  const float* lbs = lb + src;
  #pragma unroll 8
  for (int r = 0; r < LR; ++r) acc = fmaf(laj[r], lbs[(size_t)r * C3], acc);
  u16 h, l; split_bf16(acc, h, l);
  whi[idx] = h; wlo[idx] = l;
}

// ---------------------------------------------------------------------------
// fp32 [n4*4] -> bf16 hi/lo split arrays
// ---------------------------------------------------------------------------
__global__ __launch_bounds__(256) void k_cvt(
    const float* __restrict__ in, u16* __restrict__ hi, u16* __restrict__ lo, int n4) {
  int i = blockIdx.x * 256 + threadIdx.x;
  if (i >= n4) return;
  float4 v = ((const float4*)in)[i];
  float f[4] = {v.x, v.y, v.z, v.w};
  ushort4 H, L;
  u16 hh, ll;
  split_bf16(f[0], hh, ll); H.x = hh; L.x = ll;
  split_bf16(f[1], hh, ll); H.y = hh; L.y = ll;
  split_bf16(f[2], hh, ll); H.z = hh; L.z = ll;
  split_bf16(f[3], hh, ll); H.w = hh; L.w = ll;
  ((ushort4*)hi)[i] = H;
  ((ushort4*)lo)[i] = L;
}

// ---------------------------------------------------------------------------
// w_proj with perm640 row map -> bf16 hi/lo
// ---------------------------------------------------------------------------
__device__ __forceinline__ int perm640(int i) {
  return (i < 214) ? 3 * i : (i < 427 ? 3 * (i - 214) + 1 : 3 * (i - 427) + 2);
}

__global__ __launch_bounds__(256) void k_cvtw(
    const float* __restrict__ wp, u16* __restrict__ hi, u16* __restrict__ lo) {
  int idx = blockIdx.x * 256 + threadIdx.x;      // covers 640*640
  int i = idx / CC, j = idx % CC;
  float v = wp[(size_t)perm640(i) * CC + j];
  u16 h, l; split_bf16(v, h, l);
  hi[idx] = h; lo[idx] = l;
}

// ---------------------------------------------------------------------------
// Split-bf16 MFMA GEMM: C[M,Nc] = (Ahi+Alo)[M,640] @ (Bhi+Blo)[Nc,640]^T + bias
// 3 passes: hi*hi + lo*hi + hi*lo. 128x128 tile, BK=64, 4 waves (2x2),
// 16x16x32 bf16 MFMA, global_load_lds width 16.
// ---------------------------------------------------------------------------
__global__ __launch_bounds__(256) void k_gemm_mfma(
    const u16* __restrict__ Ahi, const u16* __restrict__ Alo,
    const u16* __restrict__ Bhi, const u16* __restrict__ Blo,
    const float* __restrict__ bias, float* __restrict__ Cc,
    int M, int Nc) {
  __shared__ u16 As[128][64];
  __shared__ u16 Bs[128][64];
  int t = threadIdx.x, w = t >> 6, l = t & 63;
  int m0 = blockIdx.x * 128, n0 = blockIdx.y * 128;
  int wr = w >> 1, wc = w & 1;
  f32x4 acc[4][4] = {};
  int srow = l >> 3;          // 0..7 row within 8-row chunk
  int scol = (l & 7) * 8;     // element offset (8 bf16 = 16B)

  const u16* pAs[3] = {Ahi, Alo, Ahi};
  const u16* pBs[3] = {Bhi, Bhi, Blo};

  for (int p = 0; p < 3; ++p) {
    const u16* pA = pAs[p];
    const u16* pB = pBs[p];
    for (int k0 = 0; k0 < 640; k0 += 64) {
      #pragma unroll
      for (int j = 0; j < 4; ++j) {
        int row = 32 * w + 8 * j + srow;
        int ga = m0 + row; if (ga >= M) ga = M - 1;
        __builtin_amdgcn_global_load_lds(
            (const __attribute__((address_space(1))) void*)(pA + (size_t)ga * 640 + k0 + scol),
            (__attribute__((address_space(3))) void*)(&As[32 * w + 8 * j][0]), 16, 0, 0);
        __builtin_amdgcn_global_load_lds(
            (const __attribute__((address_space(1))) void*)(pB + (size_t)(n0 + 32 * w + 8 * j + srow) * 640 + k0 + scol),
            (__attribute__((address_space(3))) void*)(&Bs[32 * w + 8 * j][0]), 16, 0, 0);
      }
      __syncthreads();
      int fr = l & 15, fq = l >> 4;
      bf16x8 a[4][2], b[4][2];
      #pragma unroll
      for (int mi = 0; mi < 4; ++mi) {
        #pragma unroll
        for (int ks = 0; ks < 2; ++ks) {
          a[mi][ks] = *(const bf16x8*)&As[wr * 64 + 16 * mi + fr][ks * 32 + fq * 8];
          b[mi][ks] = *(const bf16x8*)&Bs[wc * 64 + 16 * mi + fr][ks * 32 + fq * 8];
        }
      }
      #pragma unroll
      for (int mi = 0; mi < 4; ++mi)
        #pragma unroll
        for (int ni = 0; ni < 4; ++ni)
          #pragma unroll
          for (int ks = 0; ks < 2; ++ks)
            acc[mi][ni] = __builtin_amdgcn_mfma_f32_16x16x32_bf16(
                a[mi][ks], b[ni][ks], acc[mi][ni], 0, 0, 0);
      __syncthreads();
    }
  }

  int fr = l & 15, fq = l >> 4;
  #pragma unroll
  for (int mi = 0; mi < 4; ++mi) {
    #pragma unroll
    for (int ni = 0; ni < 4; ++ni) {
      int col = n0 + wc * 64 + 16 * ni + fr;
      float bv = bias[col];
      #pragma unroll
      for (int r = 0; r < 4; ++r) {
        int row = m0 + wr * 64 + 16 * mi + fq * 4 + r;
        if (row < M) Cc[(size_t)row * Nc + col] = acc[mi][ni][r] + bv;
      }
    }
  }
}

// ---------------------------------------------------------------------------
// K4: scores + softmax per (b,h); blockIdx.y chunks q-groups (5 x 12 groups)
// ---------------------------------------------------------------------------
__global__ __launch_bounds__(256) void k_scores(
    const float* __restrict__ qkv, const float* __restrict__ tkv,
    const float* __restrict__ tkh, float* __restrict__ attnP) {
  __shared__ float4 Kt4[16][201];      // [d4][k]
  __shared__ float4 Tk4[16][65];       // [d4][c]  c<30: tab_k_v, 32..61: tab_k_h
  __shared__ float4 Q4w[4][16][4];     // [wave][d4][r]
  __shared__ float  PvPh[4][4][64];    // [wave][r][c]
  int bh = blockIdx.x;
  int b = bh / HH, h = bh % HH;
  int t = threadIdx.x, w = t >> 6, l = t & 63;
  const float* qbase = qkv + (size_t)b * NN * C3 + h * DD;

  for (int id = t; id < NN * 16; id += 256) {
    int k = id >> 4, d4 = id & 15;
    Kt4[d4][k] = *(const float4*)(qbase + (size_t)k * C3 + CC + 4 * d4);
  }
  for (int id = t; id < 1024; id += 256) {
    int c = id >> 4, d4 = id & 15;
    float4 v = make_float4(0.f, 0.f, 0.f, 0.f);
    if (c < 30) v = *(const float4*)(tkv + c * DD + 4 * d4);
    else if (c >= 32 && c < 62) v = *(const float4*)(tkh + (c - 32) * DD + 4 * d4);
    Tk4[d4][c] = v;
  }
  __syncthreads();

  float* attnBase = attnP + (size_t)bh * NN * 200;
  int g0 = 12 * blockIdx.y;
  int gend = min(50, g0 + 12);
  for (int g = g0 + w; g < gend; g += 4) {
    int q0 = 4 * g;
    {
      int r = l >> 4, d4 = l & 15;
      int q = q0 + r;
      float4 v = make_float4(0.f, 0.f, 0.f, 0.f);
      if (q < NN) v = *(const float4*)(qbase + (size_t)q * C3 + 4 * d4);
      Q4w[w][d4][r] = v;
    }
    float pv[4] = {0.f, 0.f, 0.f, 0.f};
    #pragma unroll
    for (int d4 = 0; d4 < 16; ++d4) {
      float4 tb = Tk4[d4][l];
      #pragma unroll
      for (int r = 0; r < 4; ++r) pv[r] += dot4(Q4w[w][d4][r], tb);
    }
    #pragma unroll
    for (int r = 0; r < 4; ++r) PvPh[w][r][l] = pv[r];

    float sc[4][4];
    #pragma unroll
    for (int r = 0; r < 4; ++r)
      #pragma unroll
      for (int i = 0; i < 4; ++i) sc[r][i] = 0.f;
    #pragma unroll
    for (int d4 = 0; d4 < 16; ++d4) {
      float4 q4[4];
      #pragma unroll
      for (int r = 0; r < 4; ++r) q4[r] = Q4w[w][d4][r];
      float4 kv = Kt4[d4][l];
      #pragma unroll
      for (int r = 0; r < 4; ++r) sc[r][0] += dot4(q4[r], kv);
      kv = Kt4[d4][l + 64];
      #pragma unroll
      for (int r = 0; r < 4; ++r) sc[r][1] += dot4(q4[r], kv);
      kv = Kt4[d4][l + 128];
      #pragma unroll
      for (int r = 0; r < 4; ++r) sc[r][2] += dot4(q4[r], kv);
      if (l < 5) {
        kv = Kt4[d4][l + 192];
        #pragma unroll
        for (int r = 0; r < 4; ++r) sc[r][3] += dot4(q4[r], kv);
      }
    }
    #pragma unroll
    for (int r = 0; r < 4; ++r) {
      int q = q0 + r;
      float s[4];
      #pragma unroll
      for (int i = 0; i < 4; ++i) {
        int k = l + 64 * i;
        if (k < NN && q < NN) {
          int fv, fh;
          if (q == 0 || k == 0) { fv = 0; fh = 0; }
          else {
            fv = (k - 1) / 14 - (q - 1) / 14 + 15;
            fh = (k - 1) % 14 - (q - 1) % 14 + 15;
          }
          s[i] = (sc[r][i] + PvPh[w][r][fv] + PvPh[w][r][32 + fh]) * SCALE;
        } else s[i] = -INFINITY;
      }
      float m = fmaxf(fmaxf(s[0], s[1]), fmaxf(s[2], s[3]));
      #pragma unroll
      for (int off = 32; off >= 1; off >>= 1) m = fmaxf(m, __shfl_xor(m, off));
      float e[4], sum = 0.f;
      #pragma unroll
      for (int i = 0; i < 4; ++i) { e[i] = __expf(s[i] - m); sum += e[i]; }
      #pragma unroll
      for (int off = 32; off >= 1; off >>= 1) sum += __shfl_xor(sum, off);
      float inv = 1.f / sum;
      if (q < NN) {
        float* rowp = attnBase + (size_t)q * 200;
        #pragma unroll
        for (int i = 0; i < 3; ++i) rowp[l + 64 * i] = e[i] * inv;
        int k3 = l + 192;
        if (k3 < NN) rowp[k3] = e[3] * inv;
        else if (k3 < 200) rowp[k3] = 0.f;
      }
    }
  }
}

// ---------------------------------------------------------------------------
// K5: AV + bucketed rel-position output
// ---------------------------------------------------------------------------
__global__ __launch_bounds__(256) void k_av(
    const float* __restrict__ qkv, const float* __restrict__ attnP,
    const float* __restrict__ tvv, const float* __restrict__ tvh,
    float* __restrict__ omid) {
  __shared__ float Vt[64][212];
  __shared__ float pL[4][4][200];
  __shared__ float AvAh[4][4][2][32];
  int bh = blockIdx.x, b = bh / HH, h = bh % HH;
  int t = threadIdx.x, w = t >> 6, l = t & 63;
  const float* vbase = qkv + (size_t)b * NN * C3 + 2 * CC + h * DD;

  for (int id = t; id < 200 * 16; id += 256) {
    int k = id >> 4, d4 = id & 15;
    float4 v = make_float4(0.f, 0.f, 0.f, 0.f);
    if (k < NN) v = *(const float4*)(vbase + (size_t)k * C3 + 4 * d4);
    Vt[4*d4+0][k] = v.x; Vt[4*d4+1][k] = v.y;
    Vt[4*d4+2][k] = v.z; Vt[4*d4+3][k] = v.w;
  }
  __syncthreads();

  const float* attnBase = attnP + (size_t)bh * NN * 200;
  float* obase = omid + (size_t)b * NN * CC + h * DD;
  for (int g = w; g < 50; g += 4) {
    int q0 = 4 * g;
    for (int id = l; id < 200; id += 64) {
      int r = id / 50, k4 = id % 50;
      int q = q0 + r;
      float4 v = make_float4(0.f, 0.f, 0.f, 0.f);
      if (q < NN) v = *(const float4*)(attnBase + (size_t)q * 200 + 4 * k4);
      *(float4*)&pL[w][r][4 * k4] = v;
    }
    float out[4] = {0.f, 0.f, 0.f, 0.f};
    const float* vrow = &Vt[l][0];
    #pragma unroll 5
    for (int k4 = 0; k4 < 50; ++k4) {
      float4 v4 = *(const float4*)(vrow + 4 * k4);
      #pragma unroll
      for (int r = 0; r < 4; ++r)
        out[r] += dot4(*(const float4*)&pL[w][r][4 * k4], v4);
    }
    #pragma unroll
    for (int r = 0; r < 4; ++r) {
      int q = q0 + r;
      float av = 0.f, ah = 0.f;
      if (q == 0) {
        if (l == 0) {
          float ss = 0.f;
          for (int k = 0; k < NN; ++k) ss += pL[w][r][k];
          av = ss; ah = ss;
        }
      } else if (q < NN) {
        int gq = (q - 1) / 14, cq = (q - 1) % 14;
        int gg = l - 15 + gq;
        if (gg >= 0 && gg < 14) {
          int base = 1 + 14 * gg;
          #pragma unroll
          for (int jj = 0; jj < 14; ++jj) av += pL[w][r][base + jj];
        }
        int cc2 = l - 15 + cq;
        if (cc2 >= 0 && cc2 < 14) {
          #pragma unroll
          for (int ii = 0; ii < 14; ++ii) ah += pL[w][r][1 + cc2 + 14 * ii];
        }
        if (l == 0) { av += pL[w][r][0]; ah += pL[w][r][0]; }
      }
      if (l < 32) { AvAh[w][r][0][l] = av; AvAh[w][r][1][l] = ah; }
    }
    #pragma unroll 1
    for (int tt = 0; tt < 30; ++tt) {
      float vv = tvv[tt * DD + l];
      float vh = tvh[tt * DD + l];
      #pragma unroll
      for (int r = 0; r < 4; ++r)
        out[r] += AvAh[w][r][0][tt] * vv + AvAh[w][r][1][tt] * vh;
    }
    #pragma unroll
    for (int r = 0; r < 4; ++r) {
      int q = q0 + r;
      if (q < NN) obase[(size_t)q * CC + l] = out[r];
    }
  }
}

// ---------------------------------------------------------------------------
// Workspace layout (231.6 MB total, all regions 16B-aligned):
//   [0]      qkv      f32  24,207,360            (live: gemm1 .. k_av)
//   [A]      attnRegion    25,216,000 f          multi-use:
//              - xhi/xlo   u16 2x8,069,120       (live: cvt .. gemm1)
//              - attn      f32 640*197*200       (live: k_scores .. k_av)
//              - ohi/olo   u16 2x8,069,120       (live: cvt2 .. gemm2)
//   [O]      omid     f32  8,069,120             multi-use:
//              - weffhi/lo u16 2x1,228,800       (live: k_weff .. gemm1)
//              - omid      f32                   (live: k_av .. cvt2)
//   [W]      wp splits u16 2x409,600             (live: k_cvtw .. gemm2)
// ---------------------------------------------------------------------------
extern "C" void kernel_launch(void* const* d_in, const int* in_sizes, int n_in,
                              void* d_out, int out_size, void* d_ws, size_t ws_size,
                              hipStream_t stream) {
  (void)in_sizes; (void)n_in; (void)out_size; (void)ws_size;
  const float* x     = (const float*)d_in[0];
  const float* w_qkv = (const float*)d_in[1];
  const float* b_qkv = (const float*)d_in[2];
  const float* la    = (const float*)d_in[3];
  const float* lb    = (const float*)d_in[4];
  const float* tkv   = (const float*)d_in[5];
  const float* tkh   = (const float*)d_in[6];
  const float* tvv   = (const float*)d_in[7];
  const float* tvh   = (const float*)d_in[8];
  const float* wp    = (const float*)d_in[9];
  const float* b_p   = (const float*)d_in[10];

  float* ws    = (float*)d_ws;
  float* qkv   = ws;                                    // 24,207,360 f
  float* attnR = qkv + (size_t)24207360;                // 25,216,000 f
  float* omid  = attnR + (size_t)25216000;              //  8,069,120 f
  float* wpR   = omid + (size_t)8069120;                //    409,600 f

  u16* xhi = (u16*)attnR;
  u16* xlo = xhi + (size_t)MTOT * CC;
  float* attn = attnR;
  u16* ohi = (u16*)attnR;
  u16* olo = ohi + (size_t)MTOT * CC;
  u16* weffhi = (u16*)omid;
  u16* wefflo = weffhi + (size_t)C3 * CC;
  u16* wphi = (u16*)wpR;
  u16* wplo = wphi + (size_t)CC * CC;

  // weights: lora-fused + perm + split (weff splits live in omid region)
  k_weff<<<(C3 * CC) / 256, 256, 0, stream>>>(w_qkv, la, lb, weffhi, wefflo);
  k_cvtw<<<(CC * CC) / 256, 256, 0, stream>>>(wp, wphi, wplo);
  // x -> hi/lo (in attn region)
  int n4x = (MTOT * CC) / 4;
  k_cvt<<<(n4x + 255) / 256, 256, 0, stream>>>(x, xhi, xlo, n4x);

  // qkv = x @ weff^T + b_qkv   (split-bf16 MFMA)
  dim3 g1((MTOT + 127) / 128, C3 / 128);
  k_gemm_mfma<<<g1, dim3(256), 0, stream>>>(xhi, xlo, weffhi, wefflo, b_qkv, qkv, MTOT, C3);

  // attn probs overwrite x-splits (dead after gemm1)
  k_scores<<<dim3(BB * HH, 5), 256, 0, stream>>>(qkv, tkv, tkh, attn);
  // omid overwrites weff splits (dead after gemm1)
  k_av<<<BB * HH, 256, 0, stream>>>(qkv, attn, tvv, tvh, omid);

  // omid -> hi/lo into attn region (attn dead after k_av)
  k_cvt<<<(n4x + 255) / 256, 256, 0, stream>>>(omid, ohi, olo, n4x);

  // out = omid @ perm3(w_proj)^T + b_proj
  dim3 g2((MTOT + 127) / 128, CC / 128);
  k_gemm_mfma<<<g2, dim3(256), 0, stream>>>(ohi, olo, wphi, wplo, b_p, (float*)d_out, MTOT, CC);
}

// Round 4
// 537.062 us; speedup vs baseline: 2.2869x; 1.7760x over previous
//
#include <hip/hip_runtime.h>
#include <math.h>

#define BB 64
#define NN 197
#define HH 10
#define DD 64
#define CC 640
#define C3 1920
#define LR 64
#define MTOT (BB*NN)          // 12608
#define SCALE 0.125f

typedef unsigned short u16;
typedef __bf16 bf16x8 __attribute__((ext_vector_type(8)));
typedef float f32x4 __attribute__((ext_vector_type(4)));

__device__ __forceinline__ void split_bf16(float f, u16& hi, u16& lo) {
  unsigned u = __float_as_uint(f);
  unsigned r = u + 0x7FFF + ((u >> 16) & 1);
  u16 hb = (u16)(r >> 16);
  float fh = __uint_as_float((unsigned)hb << 16);
  float dl = f - fh;
  unsigned u2 = __float_as_uint(dl);
  unsigned r2 = u2 + 0x7FFF + ((u2 >> 16) & 1);
  hi = hb; lo = (u16)(r2 >> 16);
}

// ---------------------------------------------------------------------------
// K1: w_eff = perm3(w_qkv + (lora_a @ lora_b)^T) -> bf16 hi/lo split
// ---------------------------------------------------------------------------
__global__ __launch_bounds__(256) void k_weff(
    const float* __restrict__ w_qkv, const float* __restrict__ la,
    const float* __restrict__ lb, u16* __restrict__ whi, u16* __restrict__ wlo) {
  int idx = blockIdx.x * 256 + threadIdx.x;      // covers 1920*640
  int i = idx / CC, j = idx % CC;
  int src = 3 * (i % CC) + (i / CC);
  float acc = w_qkv[(size_t)src * CC + j];
  const float* laj = la + (size_t)j * LR;
  const float* lbs = lb + src;
  #pragma unroll 8
  for (int r = 0; r < LR; ++r) acc = fmaf(laj[r], lbs[(size_t)r * C3], acc);
  u16 h, l; split_bf16(acc, h, l);
  whi[idx] = h; wlo[idx] = l;
}

// fp32 -> bf16 hi/lo split
__global__ __launch_bounds__(256) void k_cvt(
    const float* __restrict__ in, u16* __restrict__ hi, u16* __restrict__ lo, int n4) {
  int i = blockIdx.x * 256 + threadIdx.x;
  if (i >= n4) return;
  float4 v = ((const float4*)in)[i];
  float f[4] = {v.x, v.y, v.z, v.w};
  ushort4 H, L;
  u16 hh, ll;
  split_bf16(f[0], hh, ll); H.x = hh; L.x = ll;
  split_bf16(f[1], hh, ll); H.y = hh; L.y = ll;
  split_bf16(f[2], hh, ll); H.z = hh; L.z = ll;
  split_bf16(f[3], hh, ll); H.w = hh; L.w = ll;
  ((ushort4*)hi)[i] = H;
  ((ushort4*)lo)[i] = L;
}

__device__ __forceinline__ int perm640(int i) {
  return (i < 214) ? 3 * i : (i < 427 ? 3 * (i - 214) + 1 : 3 * (i - 427) + 2);
}

__global__ __launch_bounds__(256) void k_cvtw(
    const float* __restrict__ wp, u16* __restrict__ hi, u16* __restrict__ lo) {
  int idx = blockIdx.x * 256 + threadIdx.x;      // covers 640*640
  int i = idx / CC, j = idx % CC;
  float v = wp[(size_t)perm640(i) * CC + j];
  u16 h, l; split_bf16(v, h, l);
  hi[idx] = h; lo[idx] = l;
}

// tabK: rows 0..29 tkv, 30..59 tkh, 60..63 zero -> bf16 hi/lo [64][64]
__global__ __launch_bounds__(256) void k_prep(
    const float* __restrict__ tkv, const float* __restrict__ tkh,
    u16* __restrict__ thi, u16* __restrict__ tlo) {
  for (int idx = threadIdx.x; idx < 4096; idx += 256) {
    int row = idx >> 6, d = idx & 63;
    float v = row < 30 ? tkv[row * 64 + d] : (row < 60 ? tkh[(row - 30) * 64 + d] : 0.f);
    u16 hh, ll; split_bf16(v, hh, ll);
    thi[idx] = hh; tlo[idx] = ll;
  }
}

// ---------------------------------------------------------------------------
// Split-bf16 MFMA GEMM: C = (Ahi+Alo)[M,640] @ (Bhi+Blo)[Nc,640]^T + bias
// OSPLIT=0: f32 out; OSPLIT=1: bf16 hi/lo split out.
// ---------------------------------------------------------------------------
template<int OSPLIT>
__global__ __launch_bounds__(256) void k_gemm_mfma(
    const u16* __restrict__ Ahi, const u16* __restrict__ Alo,
    const u16* __restrict__ Bhi, const u16* __restrict__ Blo,
    const float* __restrict__ bias, float* __restrict__ Cc,
    u16* __restrict__ Chi, u16* __restrict__ Clo,
    int M, int Nc) {
  __shared__ u16 As[128][64];
  __shared__ u16 Bs[128][64];
  int t = threadIdx.x, w = t >> 6, l = t & 63;
  int m0 = blockIdx.x * 128, n0 = blockIdx.y * 128;
  int wr = w >> 1, wc = w & 1;
  f32x4 acc[4][4] = {};
  int srow = l >> 3;
  int scol = (l & 7) * 8;

  const u16* pAs[3] = {Ahi, Alo, Ahi};
  const u16* pBs[3] = {Bhi, Bhi, Blo};

  for (int p = 0; p < 3; ++p) {
    const u16* pA = pAs[p];
    const u16* pB = pBs[p];
    for (int k0 = 0; k0 < 640; k0 += 64) {
      #pragma unroll
      for (int j = 0; j < 4; ++j) {
        int row = 32 * w + 8 * j + srow;
        int ga = m0 + row; if (ga >= M) ga = M - 1;
        __builtin_amdgcn_global_load_lds(
            (const __attribute__((address_space(1))) void*)(pA + (size_t)ga * 640 + k0 + scol),
            (__attribute__((address_space(3))) void*)(&As[32 * w + 8 * j][0]), 16, 0, 0);
        __builtin_amdgcn_global_load_lds(
            (const __attribute__((address_space(1))) void*)(pB + (size_t)(n0 + 32 * w + 8 * j + srow) * 640 + k0 + scol),
            (__attribute__((address_space(3))) void*)(&Bs[32 * w + 8 * j][0]), 16, 0, 0);
      }
      __syncthreads();
      int fr = l & 15, fq = l >> 4;
      bf16x8 a[4][2], b[4][2];
      #pragma unroll
      for (int mi = 0; mi < 4; ++mi) {
        #pragma unroll
        for (int ks = 0; ks < 2; ++ks) {
          a[mi][ks] = *(const bf16x8*)&As[wr * 64 + 16 * mi + fr][ks * 32 + fq * 8];
          b[mi][ks] = *(const bf16x8*)&Bs[wc * 64 + 16 * mi + fr][ks * 32 + fq * 8];
        }
      }
      #pragma unroll
      for (int mi = 0; mi < 4; ++mi)
        #pragma unroll
        for (int ni = 0; ni < 4; ++ni)
          #pragma unroll
          for (int ks = 0; ks < 2; ++ks)
            acc[mi][ni] = __builtin_amdgcn_mfma_f32_16x16x32_bf16(
                a[mi][ks], b[ni][ks], acc[mi][ni], 0, 0, 0);
      __syncthreads();
    }
  }

  int fr = l & 15, fq = l >> 4;
  #pragma unroll
  for (int mi = 0; mi < 4; ++mi) {
    #pragma unroll
    for (int ni = 0; ni < 4; ++ni) {
      int col = n0 + wc * 64 + 16 * ni + fr;
      float bv = bias[col];
      #pragma unroll
      for (int r = 0; r < 4; ++r) {
        int row = m0 + wr * 64 + 16 * mi + fq * 4 + r;
        if (row < M) {
          float val = acc[mi][ni][r] + bv;
          if (OSPLIT) {
            u16 hh, ll; split_bf16(val, hh, ll);
            Chi[(size_t)row * Nc + col] = hh;
            Clo[(size_t)row * Nc + col] = ll;
          } else {
            Cc[(size_t)row * Nc + col] = val;
          }
        }
      }
    }
  }
}

// ---------------------------------------------------------------------------
// Fused MFMA attention. Block = (b,h, q-tile of 64 rows). 4 waves; wave w owns
// 16 q-rows. Split-bf16 3-pass everywhere. Rel-k tables appended as K-tile
// rows 208..271 (S-frags 13..16 = Pv/Ph). Rel-v via 0/1 bucket matrix M as
// V-tile n-rows 64..95 (Bv/Bh = P@M), shift-gather fp32 epilogue.
// ---------------------------------------------------------------------------
__global__ __launch_bounds__(256) void k_attn(
    const u16* __restrict__ qkvhi, const u16* __restrict__ qkvlo,
    const u16* __restrict__ tabKhi, const u16* __restrict__ tabKlo,
    const float* __restrict__ tvv, const float* __restrict__ tvh,
    u16* __restrict__ ohi, u16* __restrict__ olo) {
  __shared__ __align__(16) unsigned char LDS[163328];
  unsigned char* Akhi = LDS;                    // [272][64]u16 swz (34816B)
  unsigned char* Aklo = LDS + 34816;            // (34816B)
  unsigned char* Aphi = LDS;                    // phase2: [64][224]u16 swz (28672B)
  unsigned char* Aplo = LDS + 28672;            // (28672B)
  unsigned char* Bvhi = LDS + 69632;            // [96][224]u16 swz (43008B) rows 64..95 = M
  unsigned char* Bvlo = LDS + 112640;           // [64][192]u16 swz (24576B)
  float* PvPh = (float*)(LDS + 137216);         // [64][60] f32 (S phase)
  float* TvvL = (float*)(LDS + 137216);         // [30][64] f32 (aliases PvPh, staged later)
  float* TvhL = (float*)(LDS + 144896);         // [30][64] f32
  float* BvBh = (float*)(LDS + 152576);         // [64][32] f32

  int bh = blockIdx.x, b = bh / HH, h = bh % HH, qt = blockIdx.y;
  int t = threadIdx.x, w = t >> 6, l = t & 63;
  int fr = l & 15, fq = l >> 4;
  int q0 = 64 * qt;
  const size_t qbase = (size_t)(b * NN) * C3;

  // Q fragments (global -> regs), rows clamped
  bf16x8 qh[2], qlo_[2];
  {
    int qg = q0 + 16 * w + fr; int qc = qg > 196 ? 196 : qg;
    const u16* qr  = qkvhi + qbase + (size_t)qc * C3 + h * DD;
    const u16* qr2 = qkvlo + qbase + (size_t)qc * C3 + h * DD;
    qh[0]   = *(const bf16x8*)(qr  + 8 * fq);
    qh[1]   = *(const bf16x8*)(qr  + 32 + 8 * fq);
    qlo_[0] = *(const bf16x8*)(qr2 + 8 * fq);
    qlo_[1] = *(const bf16x8*)(qr2 + 32 + 8 * fq);
  }

  // ---- phase 1: stage K (glds, pre-swizzled source) + V^T/M (scalar, swz) ----
  int kr = l >> 3;
  int chunk = ((l & 7) ^ (kr & 7)) * 8;   // u16 units
  for (int i = w; i < 25; i += 4) {
    int kk = 8 * i + kr; if (kk > 196) kk = 196;
    const u16* sh = qkvhi + qbase + (size_t)kk * C3 + CC + h * DD + chunk;
    const u16* sl = qkvlo + qbase + (size_t)kk * C3 + CC + h * DD + chunk;
    __builtin_amdgcn_global_load_lds((const __attribute__((address_space(1))) void*)sh,
        (__attribute__((address_space(3))) void*)(Akhi + i * 1024), 16, 0, 0);
    __builtin_amdgcn_global_load_lds((const __attribute__((address_space(1))) void*)sl,
        (__attribute__((address_space(3))) void*)(Aklo + i * 1024), 16, 0, 0);
  }
  for (int i = w; i < 8; i += 4) {
    int tr = 8 * i + kr;
    __builtin_amdgcn_global_load_lds(
        (const __attribute__((address_space(1))) void*)(tabKhi + tr * 64 + chunk),
        (__attribute__((address_space(3))) void*)(Akhi + 26624 + i * 1024), 16, 0, 0);
    __builtin_amdgcn_global_load_lds(
        (const __attribute__((address_space(1))) void*)(tabKlo + tr * 64 + chunk),
        (__attribute__((address_space(3))) void*)(Aklo + 26624 + i * 1024), 16, 0, 0);
  }
  // V^T (d-major) rows 0..63, k 0..196 (lo only k<192), swizzled scalar writes
  for (int idx = t; idx < 1576; idx += 256) {
    int k = idx >> 3, d0 = (idx & 7) * 8;
    size_t off = qbase + (size_t)k * C3 + 2 * CC + h * DD + d0;
    uint4 vh4 = *(const uint4*)(qkvhi + off);
    uint4 vl4 = *(const uint4*)(qkvlo + off);
    u16 eh[8] = {(u16)vh4.x, (u16)(vh4.x >> 16), (u16)vh4.y, (u16)(vh4.y >> 16),
                 (u16)vh4.z, (u16)(vh4.z >> 16), (u16)vh4.w, (u16)(vh4.w >> 16)};
    u16 el[8] = {(u16)vl4.x, (u16)(vl4.x >> 16), (u16)vl4.y, (u16)(vl4.y >> 16),
                 (u16)vl4.z, (u16)(vl4.z >> 16), (u16)vl4.w, (u16)(vl4.w >> 16)};
    #pragma unroll
    for (int jj = 0; jj < 8; ++jj) {
      int d = d0 + jj;
      int byte = (d * 224 + k) * 2; byte ^= (d & 7) << 4;
      *(u16*)(Bvhi + byte) = eh[jj];
      if (k < 192) {
        int byteL = (d * 192 + k) * 2; byteL ^= (d & 7) << 4;
        *(u16*)(Bvlo + byteL) = el[jj];
      }
    }
  }
  // V zero-pad k 197..223, rows 0..63 (hi)
  for (int idx = t; idx < 64 * 27; idx += 256) {
    int d = idx / 27, k = 197 + idx % 27;
    int byte = (d * 224 + k) * 2; byte ^= (d & 7) << 4;
    *(u16*)(Bvhi + byte) = 0;
  }
  // M one-hot rows 64..95 (all k, zero beyond 196)
  for (int idx = t; idx < 32 * 224; idx += 256) {
    int ar = idx / 224, k = idx % 224;
    u16 v = 0;
    if (k < 197) {
      int a1 = (k == 0) ? 14 : (k - 1) / 14;
      int a2 = (k == 0) ? 14 : (k - 1) % 14;
      if (ar == a1) v = 0x3F80;
      if (ar == 16 + a2) v = 0x3F80;
    }
    int vrow = 64 + ar;
    int byte = (vrow * 224 + k) * 2; byte ^= (vrow & 7) << 4;
    *(u16*)(Bvhi + byte) = v;
  }
  __syncthreads();   // barrier 1: staging done

  // ---- S = Q K^T (+tables), 3-pass split, 17 n-frags ----
  f32x4 sacc[17] = {};
  #pragma unroll
  for (int ks = 0; ks < 2; ++ks)
    #pragma unroll
    for (int nf = 0; nf < 17; ++nf) {
      int row = 16 * nf + fr;
      int byte = row * 128 + 64 * ks + 16 * fq; byte ^= (row & 7) << 4;
      bf16x8 bhf = *(const bf16x8*)(Akhi + byte);
      bf16x8 blf = *(const bf16x8*)(Aklo + byte);
      sacc[nf] = __builtin_amdgcn_mfma_f32_16x16x32_bf16(qh[ks],  bhf, sacc[nf], 0, 0, 0);
      sacc[nf] = __builtin_amdgcn_mfma_f32_16x16x32_bf16(qlo_[ks], bhf, sacc[nf], 0, 0, 0);
      sacc[nf] = __builtin_amdgcn_mfma_f32_16x16x32_bf16(qh[ks],  blf, sacc[nf], 0, 0, 0);
    }

  // Pv/Ph (frags 13..16) -> LDS (wave-local rows)
  #pragma unroll
  for (int nf = 13; nf < 17; ++nf)
    #pragma unroll
    for (int r = 0; r < 4; ++r) {
      int c = 16 * (nf - 13) + fr;
      if (c < 60) {
        int ql2 = 16 * w + 4 * fq + r;
        PvPh[ql2 * 60 + c] = sacc[nf][r];
      }
    }

  // gather + scale, row-max, exp, sum (wave-local PvPh reads only)
  float ex[13][4];
  float mrow[4] = {-1e30f, -1e30f, -1e30f, -1e30f};
  #pragma unroll
  for (int r = 0; r < 4; ++r) {
    int ql2 = 16 * w + 4 * fq + r; int qg = q0 + ql2;
    bool vq = qg < 197;
    int gq = (qg > 0) ? (qg - 1) / 14 : 0;
    int cq = (qg > 0) ? (qg - 1) % 14 : 0;
    #pragma unroll
    for (int nf = 0; nf < 13; ++nf) {
      int k = 16 * nf + fr;
      float s;
      if (k < 197) {
        if (vq) {
          int fv  = (qg == 0 || k == 0) ? 0 : ((k - 1) / 14 - gq + 15);
          int fh2 = (qg == 0 || k == 0) ? 0 : ((k - 1) % 14 - cq + 15);
          s = (sacc[nf][r] + PvPh[ql2 * 60 + fv] + PvPh[ql2 * 60 + 30 + fh2]) * SCALE;
        } else s = 0.f;
      } else s = -1e30f;
      ex[nf][r] = s;
      mrow[r] = fmaxf(mrow[r], s);
    }
  }
  #pragma unroll
  for (int r = 0; r < 4; ++r) {
    #pragma unroll
    for (int mk = 1; mk < 16; mk <<= 1) mrow[r] = fmaxf(mrow[r], __shfl_xor(mrow[r], mk));
  }
  float sum[4] = {0.f, 0.f, 0.f, 0.f};
  #pragma unroll
  for (int nf = 0; nf < 13; ++nf)
    #pragma unroll
    for (int r = 0; r < 4; ++r) {
      ex[nf][r] = __expf(ex[nf][r] - mrow[r]);
      sum[r] += ex[nf][r];
    }
  #pragma unroll
  for (int r = 0; r < 4; ++r) {
    #pragma unroll
    for (int mk = 1; mk < 16; mk <<= 1) sum[r] += __shfl_xor(sum[r], mk);
  }
  float inv[4];
  #pragma unroll
  for (int r = 0; r < 4; ++r) inv[r] = 1.f / sum[r];

  __syncthreads();   // barrier 2: K dead (P overwrites), PvPh dead (Tvv overwrites)

  // ---- write P (bf16 hi/lo, swz, cols 197..223 zeroed) + stage Tvv/Tvh ----
  #pragma unroll
  for (int nf = 0; nf < 14; ++nf)
    #pragma unroll
    for (int r = 0; r < 4; ++r) {
      int k = 16 * nf + fr;
      int ql2 = 16 * w + 4 * fq + r;
      float p = (nf < 13 && k < 197) ? ex[nf][r] * inv[r] : 0.f;
      u16 ph, pl; split_bf16(p, ph, pl);
      int byte = (ql2 * 224 + k) * 2; byte ^= (ql2 & 7) << 4;
      *(u16*)(Aphi + byte) = ph;
      *(u16*)(Aplo + byte) = pl;
    }
  for (int idx = t; idx < 1920; idx += 256) { TvvL[idx] = tvv[idx]; TvhL[idx] = tvh[idx]; }

  // ---- AV (+Bv/Bh via M frags), 3-pass split ----
  f32x4 oacc[6] = {};
  int prow = 16 * w + fr;
  int pswz = (fr & 7) << 4;
  #pragma unroll
  for (int ks = 0; ks < 7; ++ks) {
    int pb = prow * 448 + 64 * ks + 16 * fq; pb ^= pswz;
    bf16x8 pah = *(const bf16x8*)(Aphi + pb);
    bf16x8 pal = *(const bf16x8*)(Aplo + pb);
    #pragma unroll
    for (int nf = 0; nf < 6; ++nf) {
      int vrow = 16 * nf + fr;
      int vb = vrow * 448 + 64 * ks + 16 * fq; vb ^= (vrow & 7) << 4;
      bf16x8 vb16 = *(const bf16x8*)(Bvhi + vb);
      oacc[nf] = __builtin_amdgcn_mfma_f32_16x16x32_bf16(pah, vb16, oacc[nf], 0, 0, 0);
      oacc[nf] = __builtin_amdgcn_mfma_f32_16x16x32_bf16(pal, vb16, oacc[nf], 0, 0, 0);
      if (nf < 4 && ks < 6) {
        int vb2 = vrow * 384 + 64 * ks + 16 * fq; vb2 ^= (vrow & 7) << 4;
        bf16x8 vl16 = *(const bf16x8*)(Bvlo + vb2);
        oacc[nf] = __builtin_amdgcn_mfma_f32_16x16x32_bf16(pah, vl16, oacc[nf], 0, 0, 0);
      }
    }
  }

  // Bv/Bh -> LDS (wave-local rows)
  #pragma unroll
  for (int r = 0; r < 4; ++r) {
    int ql2 = 16 * w + 4 * fq + r;
    BvBh[ql2 * 32 + fr]      = oacc[4][r];
    BvBh[ql2 * 32 + 16 + fr] = oacc[5][r];
  }
  __syncthreads();   // barrier 3: Tvv/Tvh visible to everyone

  // ---- epilogue: rel-v shift gather + split store ----
  #pragma unroll
  for (int r = 0; r < 4; ++r) {
    int ql2 = 16 * w + 4 * fq + r; int qg = q0 + ql2;
    if (qg >= 197) continue;
    float o[4] = {oacc[0][r], oacc[1][r], oacc[2][r], oacc[3][r]};
    if (qg == 0) {
      float sv = 0.f, sh2 = 0.f;
      #pragma unroll
      for (int a = 0; a < 15; ++a) { sv += BvBh[ql2 * 32 + a]; sh2 += BvBh[ql2 * 32 + 16 + a]; }
      #pragma unroll
      for (int nf = 0; nf < 4; ++nf) {
        int d = 16 * nf + fr;
        o[nf] += sv * TvvL[d] + sh2 * TvhL[d];
      }
    } else {
      int gq = (qg - 1) / 14, cq = (qg - 1) % 14;
      float cv = BvBh[ql2 * 32 + 14], ch = BvBh[ql2 * 32 + 30];
      #pragma unroll
      for (int nf = 0; nf < 4; ++nf) {
        int d = 16 * nf + fr;
        o[nf] += cv * TvvL[d] + ch * TvhL[d];
      }
      for (int a = 0; a < 14; ++a) {
        float cva = BvBh[ql2 * 32 + a], cha = BvBh[ql2 * 32 + 16 + a];
        int rv = (a + 15 - gq) * 64, rh = (a + 15 - cq) * 64;
        #pragma unroll
        for (int nf = 0; nf < 4; ++nf) {
          int d = 16 * nf + fr;
          o[nf] += cva * TvvL[rv + d] + cha * TvhL[rh + d];
        }
      }
    }
    size_t ob = (size_t)(b * NN + qg) * CC + h * DD;
    #pragma unroll
    for (int nf = 0; nf < 4; ++nf) {
      int d = 16 * nf + fr;
      u16 hh, ll; split_bf16(o[nf], hh, ll);
      ohi[ob + d] = hh; olo[ob + d] = ll;
    }
  }
}

// ---------------------------------------------------------------------------
// Workspace (u16 units, 135.7 MB total):
//   qkvhi 24,207,360 | qkvlo 24,207,360 | xhi 8,069,120 (reused as ohi)
//   xlo 8,069,120 (reused as olo) | weffhi/lo 2x1,228,800 | wphi/lo 2x409,600
//   tabKhi/lo 2x4,096
// ---------------------------------------------------------------------------
extern "C" void kernel_launch(void* const* d_in, const int* in_sizes, int n_in,
                              void* d_out, int out_size, void* d_ws, size_t ws_size,
                              hipStream_t stream) {
  (void)in_sizes; (void)n_in; (void)out_size; (void)ws_size;
  const float* x     = (const float*)d_in[0];
  const float* w_qkv = (const float*)d_in[1];
  const float* b_qkv = (const float*)d_in[2];
  const float* la    = (const float*)d_in[3];
  const float* lb    = (const float*)d_in[4];
  const float* tkv   = (const float*)d_in[5];
  const float* tkh   = (const float*)d_in[6];
  const float* tvv   = (const float*)d_in[7];
  const float* tvh   = (const float*)d_in[8];
  const float* wp    = (const float*)d_in[9];
  const float* b_p   = (const float*)d_in[10];

  u16* qkvhi  = (u16*)d_ws;
  u16* qkvlo  = qkvhi + (size_t)24207360;
  u16* xhi    = qkvlo + (size_t)24207360;
  u16* xlo    = xhi + (size_t)8069120;
  u16* ohi    = xhi;                       // alias (x splits dead after gemm1)
  u16* olo    = xlo;
  u16* weffhi = xlo + (size_t)8069120;
  u16* wefflo = weffhi + (size_t)1228800;
  u16* wphi   = wefflo + (size_t)1228800;
  u16* wplo   = wphi + (size_t)409600;
  u16* tabKhi = wplo + (size_t)409600;
  u16* tabKlo = tabKhi + (size_t)4096;

  k_weff<<<(C3 * CC) / 256, 256, 0, stream>>>(w_qkv, la, lb, weffhi, wefflo);
  k_cvtw<<<(CC * CC) / 256, 256, 0, stream>>>(wp, wphi, wplo);
  k_prep<<<1, 256, 0, stream>>>(tkv, tkh, tabKhi, tabKlo);
  int n4x = (MTOT * CC) / 4;
  k_cvt<<<(n4x + 255) / 256, 256, 0, stream>>>(x, xhi, xlo, n4x);

  // qkv = x @ weff^T + b_qkv -> split bf16 output
  dim3 g1((MTOT + 127) / 128, C3 / 128);
  k_gemm_mfma<1><<<g1, dim3(256), 0, stream>>>(xhi, xlo, weffhi, wefflo, b_qkv,
                                               nullptr, qkvhi, qkvlo, MTOT, C3);

  // fused attention -> ohi/olo split
  k_attn<<<dim3(BB * HH, 4), 256, 0, stream>>>(qkvhi, qkvlo, tabKhi, tabKlo,
                                               tvv, tvh, ohi, olo);

  // out = o @ perm3(w_proj)^T + b_proj
  dim3 g2((MTOT + 127) / 128, CC / 128);
  k_gemm_mfma<0><<<g2, dim3(256), 0, stream>>>(ohi, olo, wphi, wplo, b_p,
                                               (float*)d_out, nullptr, nullptr, MTOT, CC);
}

// Round 5
// 396.331 us; speedup vs baseline: 3.0990x; 1.3551x over previous
//
#include <hip/hip_runtime.h>
#include <math.h>

#define BB 64
#define NN 197
#define HH 10
#define DD 64
#define CC 640
#define C3 1920
#define LR 64
#define MTOT (BB*NN)          // 12608
#define SCALE 0.125f

typedef unsigned short u16;
typedef __bf16 bf16x8 __attribute__((ext_vector_type(8)));
typedef float f32x4 __attribute__((ext_vector_type(4)));

__device__ __forceinline__ void split_bf16(float f, u16& hi, u16& lo) {
  unsigned u = __float_as_uint(f);
  unsigned r = u + 0x7FFF + ((u >> 16) & 1);
  u16 hb = (u16)(r >> 16);
  float fh = __uint_as_float((unsigned)hb << 16);
  float dl = f - fh;
  unsigned u2 = __float_as_uint(dl);
  unsigned r2 = u2 + 0x7FFF + ((u2 >> 16) & 1);
  hi = hb; lo = (u16)(r2 >> 16);
}

// ---------------------------------------------------------------------------
// K1: w_eff = perm3(w_qkv + (lora_a @ lora_b)^T) -> bf16 hi/lo split
// ---------------------------------------------------------------------------
__global__ __launch_bounds__(256) void k_weff(
    const float* __restrict__ w_qkv, const float* __restrict__ la,
    const float* __restrict__ lb, u16* __restrict__ whi, u16* __restrict__ wlo) {
  int idx = blockIdx.x * 256 + threadIdx.x;      // covers 1920*640
  int i = idx / CC, j = idx % CC;
  int src = 3 * (i % CC) + (i / CC);
  float acc = w_qkv[(size_t)src * CC + j];
  const float* laj = la + (size_t)j * LR;
  const float* lbs = lb + src;
  #pragma unroll 8
  for (int r = 0; r < LR; ++r) acc = fmaf(laj[r], lbs[(size_t)r * C3], acc);
  u16 h, l; split_bf16(acc, h, l);
  whi[idx] = h; wlo[idx] = l;
}

// fp32 -> bf16 hi/lo split
__global__ __launch_bounds__(256) void k_cvt(
    const float* __restrict__ in, u16* __restrict__ hi, u16* __restrict__ lo, int n4) {
  int i = blockIdx.x * 256 + threadIdx.x;
  if (i >= n4) return;
  float4 v = ((const float4*)in)[i];
  float f[4] = {v.x, v.y, v.z, v.w};
  ushort4 H, L;
  u16 hh, ll;
  split_bf16(f[0], hh, ll); H.x = hh; L.x = ll;
  split_bf16(f[1], hh, ll); H.y = hh; L.y = ll;
  split_bf16(f[2], hh, ll); H.z = hh; L.z = ll;
  split_bf16(f[3], hh, ll); H.w = hh; L.w = ll;
  ((ushort4*)hi)[i] = H;
  ((ushort4*)lo)[i] = L;
}

__device__ __forceinline__ int perm640(int i) {
  return (i < 214) ? 3 * i : (i < 427 ? 3 * (i - 214) + 1 : 3 * (i - 427) + 2);
}

__global__ __launch_bounds__(256) void k_cvtw(
    const float* __restrict__ wp, u16* __restrict__ hi, u16* __restrict__ lo) {
  int idx = blockIdx.x * 256 + threadIdx.x;      // covers 640*640
  int i = idx / CC, j = idx % CC;
  float v = wp[(size_t)perm640(i) * CC + j];
  u16 h, l; split_bf16(v, h, l);
  hi[idx] = h; lo[idx] = l;
}

// tabK: rows 0..29 tkv, 30..59 tkh, 60..63 zero -> bf16 hi/lo [64][64]
__global__ __launch_bounds__(256) void k_prep(
    const float* __restrict__ tkv, const float* __restrict__ tkh,
    u16* __restrict__ thi, u16* __restrict__ tlo) {
  for (int idx = threadIdx.x; idx < 4096; idx += 256) {
    int row = idx >> 6, d = idx & 63;
    float v = row < 30 ? tkv[row * 64 + d] : (row < 60 ? tkh[(row - 30) * 64 + d] : 0.f);
    u16 hh, ll; split_bf16(v, hh, ll);
    thi[idx] = hh; tlo[idx] = ll;
  }
}

// ---------------------------------------------------------------------------
// Split-bf16 MFMA GEMM, FUSED 3-pass: per k-step stage Ahi/Alo/Bhi/Blo once,
// 3 MFMAs (hh, lh, hl) per fragment pair. 128x128 tile, BK=64, 4 waves.
// ---------------------------------------------------------------------------
template<int OSPLIT>
__global__ __launch_bounds__(256) void k_gemm_mfma(
    const u16* __restrict__ Ahi, const u16* __restrict__ Alo,
    const u16* __restrict__ Bhi, const u16* __restrict__ Blo,
    const float* __restrict__ bias, float* __restrict__ Cc,
    u16* __restrict__ Chi, u16* __restrict__ Clo,
    int M, int Nc) {
  __shared__ u16 AsH[128][64];
  __shared__ u16 AsL[128][64];
  __shared__ u16 BsH[128][64];
  __shared__ u16 BsL[128][64];
  int t = threadIdx.x, w = t >> 6, l = t & 63;
  int m0 = blockIdx.x * 128, n0 = blockIdx.y * 128;
  int wr = w >> 1, wc = w & 1;
  f32x4 acc[4][4] = {};
  int srow = l >> 3;
  int scol = (l & 7) * 8;

  for (int k0 = 0; k0 < 640; k0 += 64) {
    #pragma unroll
    for (int j = 0; j < 4; ++j) {
      int row = 32 * w + 8 * j + srow;
      int ga = m0 + row; if (ga >= M) ga = M - 1;
      size_t offA = (size_t)ga * 640 + k0 + scol;
      size_t offB = (size_t)(n0 + row) * 640 + k0 + scol;
      __builtin_amdgcn_global_load_lds(
          (const __attribute__((address_space(1))) void*)(Ahi + offA),
          (__attribute__((address_space(3))) void*)(&AsH[32 * w + 8 * j][0]), 16, 0, 0);
      __builtin_amdgcn_global_load_lds(
          (const __attribute__((address_space(1))) void*)(Alo + offA),
          (__attribute__((address_space(3))) void*)(&AsL[32 * w + 8 * j][0]), 16, 0, 0);
      __builtin_amdgcn_global_load_lds(
          (const __attribute__((address_space(1))) void*)(Bhi + offB),
          (__attribute__((address_space(3))) void*)(&BsH[32 * w + 8 * j][0]), 16, 0, 0);
      __builtin_amdgcn_global_load_lds(
          (const __attribute__((address_space(1))) void*)(Blo + offB),
          (__attribute__((address_space(3))) void*)(&BsL[32 * w + 8 * j][0]), 16, 0, 0);
    }
    __syncthreads();
    int fr = l & 15, fq = l >> 4;
    #pragma unroll
    for (int ks = 0; ks < 2; ++ks) {
      bf16x8 ah[4], al[4], bh[4], bl[4];
      #pragma unroll
      for (int mi = 0; mi < 4; ++mi) {
        ah[mi] = *(const bf16x8*)&AsH[wr * 64 + 16 * mi + fr][ks * 32 + fq * 8];
        al[mi] = *(const bf16x8*)&AsL[wr * 64 + 16 * mi + fr][ks * 32 + fq * 8];
        bh[mi] = *(const bf16x8*)&BsH[wc * 64 + 16 * mi + fr][ks * 32 + fq * 8];
        bl[mi] = *(const bf16x8*)&BsL[wc * 64 + 16 * mi + fr][ks * 32 + fq * 8];
      }
      #pragma unroll
      for (int mi = 0; mi < 4; ++mi)
        #pragma unroll
        for (int ni = 0; ni < 4; ++ni) {
          acc[mi][ni] = __builtin_amdgcn_mfma_f32_16x16x32_bf16(ah[mi], bh[ni], acc[mi][ni], 0, 0, 0);
          acc[mi][ni] = __builtin_amdgcn_mfma_f32_16x16x32_bf16(al[mi], bh[ni], acc[mi][ni], 0, 0, 0);
          acc[mi][ni] = __builtin_amdgcn_mfma_f32_16x16x32_bf16(ah[mi], bl[ni], acc[mi][ni], 0, 0, 0);
        }
    }
    __syncthreads();
  }

  int fr = l & 15, fq = l >> 4;
  #pragma unroll
  for (int mi = 0; mi < 4; ++mi) {
    #pragma unroll
    for (int ni = 0; ni < 4; ++ni) {
      int col = n0 + wc * 64 + 16 * ni + fr;
      float bv = bias[col];
      #pragma unroll
      for (int r = 0; r < 4; ++r) {
        int row = m0 + wr * 64 + 16 * mi + fq * 4 + r;
        if (row < M) {
          float val = acc[mi][ni][r] + bv;
          if (OSPLIT) {
            u16 hh, ll; split_bf16(val, hh, ll);
            Chi[(size_t)row * Nc + col] = hh;
            Clo[(size_t)row * Nc + col] = ll;
          } else {
            Cc[(size_t)row * Nc + col] = val;
          }
        }
      }
    }
  }
}

// ---------------------------------------------------------------------------
// Fused MFMA attention, 512 threads (8 waves = 2/SIMD), q-tile 128.
// Wave w owns q-rows q0+16w..+15 for S/softmax. AV runs as two 64-q passes
// (P overlays dead K region). Rel-k via appended table rows (S-frags 13..16);
// rel-v via 0/1 bucket matrix M rows in the V tile + fp32 shift-gather.
// LDS 158,720 B with liveness overlays:
//   [0,34816)   Akhi[272][64]       | post-B2: Phi[64][224] @0, Plo @28672
//   [34816,69632) Aklo[272][64]     | post-B2: Vlo[64][224] @57344..86016
//   [69632,100352) PvPh[128][60]f32 | post-B2: BvBh[64][32]f32 @86016
//   [100352,143360) Bvhi+M [96][224]
//   [143360,158720) TvvL/TvhL [30][64]f32 each
// ---------------------------------------------------------------------------
__global__ __launch_bounds__(512, 2) void k_attn(
    const u16* __restrict__ qkvhi, const u16* __restrict__ qkvlo,
    const u16* __restrict__ tabKhi, const u16* __restrict__ tabKlo,
    const float* __restrict__ tvv, const float* __restrict__ tvh,
    u16* __restrict__ ohi, u16* __restrict__ olo) {
  __shared__ __align__(16) unsigned char LDS[158720];
  unsigned char* Akhi = LDS;
  unsigned char* Aklo = LDS + 34816;
  float* PvPh = (float*)(LDS + 69632);
  unsigned char* Bvhi = LDS + 100352;
  float* TvvL = (float*)(LDS + 143360);
  float* TvhL = (float*)(LDS + 151040);
  unsigned char* Phi = LDS;
  unsigned char* Plo = LDS + 28672;
  unsigned char* Bvlo = LDS + 57344;
  float* BvBh = (float*)(LDS + 86016);

  int bh = blockIdx.x, b = bh / HH, h = bh % HH, qt = blockIdx.y;
  int t = threadIdx.x, w = t >> 6, l = t & 63;
  int fr = l & 15, fq = l >> 4;
  int q0 = 128 * qt;
  const size_t qbase = (size_t)(b * NN) * C3;

  // ---- phase 1 staging ----
  int kr = l >> 3;
  int chunk = ((l & 7) ^ (kr & 7)) * 8;     // pre-swizzled source col (elems)
  for (int i = w; i < 26; i += 8) {          // K rows 0..207 (197+ clamped dups)
    int kk = 8 * i + kr; if (kk > 196) kk = 196;
    size_t src = qbase + (size_t)kk * C3 + CC + h * DD + chunk;
    __builtin_amdgcn_global_load_lds(
        (const __attribute__((address_space(1))) void*)(qkvhi + src),
        (__attribute__((address_space(3))) void*)(Akhi + i * 1024), 16, 0, 0);
    __builtin_amdgcn_global_load_lds(
        (const __attribute__((address_space(1))) void*)(qkvlo + src),
        (__attribute__((address_space(3))) void*)(Aklo + i * 1024), 16, 0, 0);
  }
  {                                          // table rows 208..271 (one chunk per wave)
    int tr = 8 * w + kr;
    __builtin_amdgcn_global_load_lds(
        (const __attribute__((address_space(1))) void*)(tabKhi + tr * 64 + chunk),
        (__attribute__((address_space(3))) void*)(Akhi + 26624 + w * 1024), 16, 0, 0);
    __builtin_amdgcn_global_load_lds(
        (const __attribute__((address_space(1))) void*)(tabKlo + tr * 64 + chunk),
        (__attribute__((address_space(3))) void*)(Aklo + 26624 + w * 1024), 16, 0, 0);
  }
  // V^T hi (d-major [64][224]), conflict-free swizzle
  for (int idx = t; idx < 1576; idx += 512) {
    int k = idx >> 3, d0 = (idx & 7) * 8;
    size_t off = qbase + (size_t)k * C3 + 2 * CC + h * DD + d0;
    uint4 vh4 = *(const uint4*)(qkvhi + off);
    u16 eh[8] = {(u16)vh4.x, (u16)(vh4.x >> 16), (u16)vh4.y, (u16)(vh4.y >> 16),
                 (u16)vh4.z, (u16)(vh4.z >> 16), (u16)vh4.w, (u16)(vh4.w >> 16)};
    #pragma unroll
    for (int jj = 0; jj < 8; ++jj) {
      int d = d0 + jj;
      int byte = (d * 224 + k) * 2; byte ^= (((d & 7) ^ ((d >> 3) & 7)) << 4);
      *(u16*)(Bvhi + byte) = eh[jj];
    }
  }
  for (int idx = t; idx < 64 * 27; idx += 512) {   // V hi pad cols 197..223
    int d = idx / 27, k = 197 + idx % 27;
    int byte = (d * 224 + k) * 2; byte ^= (((d & 7) ^ ((d >> 3) & 7)) << 4);
    *(u16*)(Bvhi + byte) = 0;
  }
  for (int idx = t; idx < 32 * 224; idx += 512) {  // M one-hot rows 64..95
    int ar = idx / 224, k = idx % 224;
    u16 v = 0;
    if (k < 197) {
      int a1 = (k == 0) ? 14 : (k - 1) / 14;
      int a2 = (k == 0) ? 14 : (k - 1) % 14;
      if (ar == a1) v = 0x3F80;
      if (ar == 16 + a2) v = 0x3F80;
    }
    int vrow = 64 + ar;
    int byte = (vrow * 224 + k) * 2; byte ^= (((vrow & 7) ^ ((vrow >> 3) & 7)) << 4);
    *(u16*)(Bvhi + byte) = v;
  }
  for (int idx = t; idx < 1920; idx += 512) { TvvL[idx] = tvv[idx]; TvhL[idx] = tvh[idx]; }

  // Q fragments
  bool active = (q0 + 16 * w) < NN;
  bf16x8 qh[2], ql_[2];
  {
    int qg = q0 + 16 * w + fr; int qc = qg > 196 ? 196 : qg;
    const u16* qr  = qkvhi + qbase + (size_t)qc * C3 + h * DD;
    const u16* qr2 = qkvlo + qbase + (size_t)qc * C3 + h * DD;
    qh[0]  = *(const bf16x8*)(qr + 8 * fq);
    qh[1]  = *(const bf16x8*)(qr + 32 + 8 * fq);
    ql_[0] = *(const bf16x8*)(qr2 + 8 * fq);
    ql_[1] = *(const bf16x8*)(qr2 + 32 + 8 * fq);
  }
  __syncthreads();   // B1: staging done

  // ---- S = Q K^T (+tables), 3-pass split ----
  float ex[13][4];
  float inv[4];
  if (active) {
    f32x4 sacc[17] = {};
    #pragma unroll
    for (int ks = 0; ks < 2; ++ks)
      #pragma unroll
      for (int nf = 0; nf < 17; ++nf) {
        int row = 16 * nf + fr;
        int byte = row * 128 + 64 * ks + 16 * fq; byte ^= (row & 7) << 4;
        bf16x8 bhf = *(const bf16x8*)(Akhi + byte);
        bf16x8 blf = *(const bf16x8*)(Aklo + byte);
        sacc[nf] = __builtin_amdgcn_mfma_f32_16x16x32_bf16(qh[ks],  bhf, sacc[nf], 0, 0, 0);
        sacc[nf] = __builtin_amdgcn_mfma_f32_16x16x32_bf16(ql_[ks], bhf, sacc[nf], 0, 0, 0);
        sacc[nf] = __builtin_amdgcn_mfma_f32_16x16x32_bf16(qh[ks],  blf, sacc[nf], 0, 0, 0);
      }
    // Pv/Ph to LDS (wave-local rows)
    #pragma unroll
    for (int nf = 13; nf < 17; ++nf)
      #pragma unroll
      for (int r = 0; r < 4; ++r) {
        int c = 16 * (nf - 13) + fr;
        if (c < 60) PvPh[(16 * w + 4 * fq + r) * 60 + c] = sacc[nf][r];
      }
    // gather + softmax
    float mrow[4] = {-1e30f, -1e30f, -1e30f, -1e30f};
    #pragma unroll
    for (int r = 0; r < 4; ++r) {
      int ql2 = 16 * w + 4 * fq + r; int qg = q0 + ql2;
      int qc = qg > 196 ? 196 : qg;
      int gq = (qc > 0) ? (qc - 1) / 14 : 0;
      int cq = (qc > 0) ? (qc - 1) % 14 : 0;
      #pragma unroll
      for (int nf = 0; nf < 13; ++nf) {
        int k = 16 * nf + fr;
        float s;
        if (k < 197) {
          int fv  = (qc == 0 || k == 0) ? 0 : ((k - 1) / 14 - gq + 15);
          int fh2 = (qc == 0 || k == 0) ? 0 : ((k - 1) % 14 - cq + 15);
          s = (sacc[nf][r] + PvPh[ql2 * 60 + fv] + PvPh[ql2 * 60 + 30 + fh2]) * SCALE;
        } else s = -1e30f;
        ex[nf][r] = s;
        mrow[r] = fmaxf(mrow[r], s);
      }
    }
    #pragma unroll
    for (int r = 0; r < 4; ++r)
      #pragma unroll
      for (int mk = 1; mk < 16; mk <<= 1) mrow[r] = fmaxf(mrow[r], __shfl_xor(mrow[r], mk));
    float sum[4] = {0.f, 0.f, 0.f, 0.f};
    #pragma unroll
    for (int nf = 0; nf < 13; ++nf)
      #pragma unroll
      for (int r = 0; r < 4; ++r) {
        ex[nf][r] = __expf(ex[nf][r] - mrow[r]);
        sum[r] += ex[nf][r];
      }
    #pragma unroll
    for (int r = 0; r < 4; ++r) {
      #pragma unroll
      for (int mk = 1; mk < 16; mk <<= 1) sum[r] += __shfl_xor(sum[r], mk);
      inv[r] = 1.f / sum[r];
    }
  }
  __syncthreads();   // B2: all S reads done; K/PvPh regions become free

  // stage V^T lo (overlay region)
  for (int idx = t; idx < 1576; idx += 512) {
    int k = idx >> 3, d0 = (idx & 7) * 8;
    size_t off = qbase + (size_t)k * C3 + 2 * CC + h * DD + d0;
    uint4 vl4 = *(const uint4*)(qkvlo + off);
    u16 el[8] = {(u16)vl4.x, (u16)(vl4.x >> 16), (u16)vl4.y, (u16)(vl4.y >> 16),
                 (u16)vl4.z, (u16)(vl4.z >> 16), (u16)vl4.w, (u16)(vl4.w >> 16)};
    #pragma unroll
    for (int jj = 0; jj < 8; ++jj) {
      int d = d0 + jj;
      int byte = (d * 224 + k) * 2; byte ^= (((d & 7) ^ ((d >> 3) & 7)) << 4);
      *(u16*)(Bvlo + byte) = el[jj];
    }
  }
  for (int idx = t; idx < 64 * 27; idx += 512) {   // V lo pad cols 197..223
    int d = idx / 27, k = 197 + idx % 27;
    int byte = (d * 224 + k) * 2; byte ^= (((d & 7) ^ ((d >> 3) & 7)) << 4);
    *(u16*)(Bvlo + byte) = 0;
  }

  int qf = w & 3, hs2 = w >> 2;
  for (int p = 0; p < 2; ++p) {
    // P-write for q-half p by owner waves (inactive/over-range rows -> zeros)
    if ((w >> 2) == p) {
      int rbase = 16 * (w & 3);
      #pragma unroll
      for (int nf = 0; nf < 14; ++nf)
        #pragma unroll
        for (int r = 0; r < 4; ++r) {
          int k = 16 * nf + fr;
          int prow = rbase + 4 * fq + r;
          float pv = 0.f;
          if (active && nf < 13 && k < 197) pv = ex[nf][r] * inv[r];
          u16 ph, pl; split_bf16(pv, ph, pl);
          int byte = (prow * 224 + k) * 2; byte ^= (prow & 7) << 4;
          *(u16*)(Phi + byte) = ph;
          *(u16*)(Plo + byte) = pl;
        }
    }
    __syncthreads();   // B3/B5: P ready

    // AV: wave -> output frag (qf, d-frags {2hs2,2hs2+1}) + M-frag hs2
    f32x4 ov0 = {}, ov1 = {}, om = {};
    {
      int prow = 16 * qf + fr;
      int vrow0 = 32 * hs2 + fr, vrow1 = vrow0 + 16;
      int mrow2 = 64 + 16 * hs2 + fr;
      int pswz = (prow & 7) << 4;
      int vswz0 = (((vrow0 & 7) ^ ((vrow0 >> 3) & 7)) << 4);
      int vswz1 = (((vrow1 & 7) ^ ((vrow1 >> 3) & 7)) << 4);
      int mswz  = (((mrow2 & 7) ^ ((mrow2 >> 3) & 7)) << 4);
      #pragma unroll
      for (int ks = 0; ks < 7; ++ks) {
        int co = 64 * ks + 16 * fq;
        bf16x8 pah = *(const bf16x8*)(Phi + ((prow * 448 + co) ^ pswz));
        bf16x8 pal = *(const bf16x8*)(Plo + ((prow * 448 + co) ^ pswz));
        bf16x8 v0h = *(const bf16x8*)(Bvhi + ((vrow0 * 448 + co) ^ vswz0));
        bf16x8 v1h = *(const bf16x8*)(Bvhi + ((vrow1 * 448 + co) ^ vswz1));
        bf16x8 v0l = *(const bf16x8*)(Bvlo + ((vrow0 * 448 + co) ^ vswz0));
        bf16x8 v1l = *(const bf16x8*)(Bvlo + ((vrow1 * 448 + co) ^ vswz1));
        bf16x8 mf  = *(const bf16x8*)(Bvhi + ((mrow2 * 448 + co) ^ mswz));
        ov0 = __builtin_amdgcn_mfma_f32_16x16x32_bf16(pah, v0h, ov0, 0, 0, 0);
        ov0 = __builtin_amdgcn_mfma_f32_16x16x32_bf16(pal, v0h, ov0, 0, 0, 0);
        ov0 = __builtin_amdgcn_mfma_f32_16x16x32_bf16(pah, v0l, ov0, 0, 0, 0);
        ov1 = __builtin_amdgcn_mfma_f32_16x16x32_bf16(pah, v1h, ov1, 0, 0, 0);
        ov1 = __builtin_amdgcn_mfma_f32_16x16x32_bf16(pal, v1h, ov1, 0, 0, 0);
        ov1 = __builtin_amdgcn_mfma_f32_16x16x32_bf16(pah, v1l, ov1, 0, 0, 0);
        om  = __builtin_amdgcn_mfma_f32_16x16x32_bf16(pah, mf, om, 0, 0, 0);
        om  = __builtin_amdgcn_mfma_f32_16x16x32_bf16(pal, mf, om, 0, 0, 0);
      }
    }
    #pragma unroll
    for (int r = 0; r < 4; ++r)
      BvBh[(16 * qf + 4 * fq + r) * 32 + 16 * hs2 + fr] = om[r];
    __syncthreads();   // B4/B6: BvBh ready

    // epilogue: rel-v shift gather + split store
    int qh0 = q0 + 64 * p;
    #pragma unroll
    for (int r = 0; r < 4; ++r) {
      int qlocal = 16 * qf + 4 * fq + r;
      int qg = qh0 + qlocal;
      if (qg >= NN) continue;
      float o0 = ov0[r], o1 = ov1[r];
      int d0 = 32 * hs2 + fr, d1 = d0 + 16;
      if (qg == 0) {
        float sv = 0.f, sh = 0.f;
        #pragma unroll
        for (int a = 0; a < 15; ++a) {
          sv += BvBh[qlocal * 32 + a];
          sh += BvBh[qlocal * 32 + 16 + a];
        }
        o0 += sv * TvvL[d0] + sh * TvhL[d0];
        o1 += sv * TvvL[d1] + sh * TvhL[d1];
      } else {
        int gq = (qg - 1) / 14, cq = (qg - 1) % 14;
        float cv = BvBh[qlocal * 32 + 14], ch = BvBh[qlocal * 32 + 30];
        o0 += cv * TvvL[d0] + ch * TvhL[d0];
        o1 += cv * TvvL[d1] + ch * TvhL[d1];
        for (int a = 0; a < 14; ++a) {
          float cva = BvBh[qlocal * 32 + a], cha = BvBh[qlocal * 32 + 16 + a];
          int rv = (a + 15 - gq) * 64, rh = (a + 15 - cq) * 64;
          o0 += cva * TvvL[rv + d0] + cha * TvhL[rh + d0];
          o1 += cva * TvvL[rv + d1] + cha * TvhL[rh + d1];
        }
      }
      size_t ob = (size_t)(b * NN + qg) * CC + h * DD;
      u16 hh, ll;
      split_bf16(o0, hh, ll); ohi[ob + d0] = hh; olo[ob + d0] = ll;
      split_bf16(o1, hh, ll); ohi[ob + d1] = hh; olo[ob + d1] = ll;
    }
  }
}

// ---------------------------------------------------------------------------
// Workspace (u16 units, 135.7 MB total):
//   qkvhi 24,207,360 | qkvlo 24,207,360 | xhi 8,069,120 (reused as ohi)
//   xlo 8,069,120 (reused as olo) | weffhi/lo 2x1,228,800 | wphi/lo 2x409,600
//   tabKhi/lo 2x4,096
// ---------------------------------------------------------------------------
extern "C" void kernel_launch(void* const* d_in, const int* in_sizes, int n_in,
                              void* d_out, int out_size, void* d_ws, size_t ws_size,
                              hipStream_t stream) {
  (void)in_sizes; (void)n_in; (void)out_size; (void)ws_size;
  const float* x     = (const float*)d_in[0];
  const float* w_qkv = (const float*)d_in[1];
  const float* b_qkv = (const float*)d_in[2];
  const float* la    = (const float*)d_in[3];
  const float* lb    = (const float*)d_in[4];
  const float* tkv   = (const float*)d_in[5];
  const float* tkh   = (const float*)d_in[6];
  const float* tvv   = (const float*)d_in[7];
  const float* tvh   = (const float*)d_in[8];
  const float* wp    = (const float*)d_in[9];
  const float* b_p   = (const float*)d_in[10];

  u16* qkvhi  = (u16*)d_ws;
  u16* qkvlo  = qkvhi + (size_t)24207360;
  u16* xhi    = qkvlo + (size_t)24207360;
  u16* xlo    = xhi + (size_t)8069120;
  u16* ohi    = xhi;                       // alias (x splits dead after gemm1)
  u16* olo    = xlo;
  u16* weffhi = xlo + (size_t)8069120;
  u16* wefflo = weffhi + (size_t)1228800;
  u16* wphi   = wefflo + (size_t)1228800;
  u16* wplo   = wphi + (size_t)409600;
  u16* tabKhi = wplo + (size_t)409600;
  u16* tabKlo = tabKhi + (size_t)4096;

  k_weff<<<(C3 * CC) / 256, 256, 0, stream>>>(w_qkv, la, lb, weffhi, wefflo);
  k_cvtw<<<(CC * CC) / 256, 256, 0, stream>>>(wp, wphi, wplo);
  k_prep<<<1, 256, 0, stream>>>(tkv, tkh, tabKhi, tabKlo);
  int n4x = (MTOT * CC) / 4;
  k_cvt<<<(n4x + 255) / 256, 256, 0, stream>>>(x, xhi, xlo, n4x);

  // qkv = x @ weff^T + b_qkv -> split bf16 output
  dim3 g1((MTOT + 127) / 128, C3 / 128);
  k_gemm_mfma<1><<<g1, dim3(256), 0, stream>>>(xhi, xlo, weffhi, wefflo, b_qkv,
                                               nullptr, qkvhi, qkvlo, MTOT, C3);

  // fused attention -> ohi/olo split
  k_attn<<<dim3(BB * HH, 2), 512, 0, stream>>>(qkvhi, qkvlo, tabKhi, tabKlo,
                                               tvv, tvh, ohi, olo);

  // out = o @ perm3(w_proj)^T + b_proj
  dim3 g2((MTOT + 127) / 128, CC / 128);
  k_gemm_mfma<0><<<g2, dim3(256), 0, stream>>>(ohi, olo, wphi, wplo, b_p,
                                               (float*)d_out, nullptr, nullptr, MTOT, CC);
}